// Round 2
// baseline (283.432 us; speedup 1.0000x reference)
//
#include <hip/hip_runtime.h>
#include <math.h>

#define BB 16
#define QQ 900
#define CC 1203
#define GG 100

constexpr int CT   = 5;             // ceil(1203/256) c-tiles
constexpr int QCH  = 20;            // q chunks
constexpr int QPC  = QQ / QCH;      // 45 q per chunk
constexpr int ABLK = CT * BB * QCH; // 1600 streaming blocks
constexpr int HB   = 8;             // batches per hier block

// Bit-exact f32 Euclidean distance (no FMA contraction), matching
// np/jnp float32: sqrt((gx-qx)^2 + (gy-qy)^2) with per-op rounding.
__device__ __forceinline__ float distf(float gx, float gy, float qx, float qy) {
  float dx = __fsub_rn(gx, qx);
  float dy = __fsub_rn(gy, qy);
  float s  = __fadd_rn(__fmul_rn(dx, dx), __fmul_rn(dy, dy));
  return __fsqrt_rn(s);
}

__global__ __launch_bounds__(256) void fused_main(
    const float* __restrict__ logits, const float* __restrict__ boxes,
    const float* __restrict__ qcen,  const float* __restrict__ gtb,
    const int* __restrict__ gtl, float* __restrict__ probs_sum,
    double* __restrict__ accs)
{
  __shared__ float s_qx[QQ], s_qy[QQ], s_gx[GG], s_gy[GG], s_ming[GG];
  __shared__ int s_order[GG], s_qs[GG];
  __shared__ unsigned long long s_r64[4];
  __shared__ double s_rd[8];

  const int bid  = blockIdx.x;
  const int tid  = threadIdx.x;
  const int lane = tid & 63;
  const int wv   = tid >> 6;

  if (bid < ABLK) {
    // ---------- pass A: focal base sum + sigmoid row-sums ----------
    int ct = bid % CT;
    int b  = (bid / CT) % BB;
    int qk = bid / (CT * BB);
    int c  = ct * 256 + tid;
    float s_sig = 0.f, s_foc = 0.f;
    if (c < CC) {
      const float* base = logits + ((size_t)b * QQ + (size_t)qk * QPC) * CC + c;
      for (int i = 0; i < QPC; ++i) {
        float x  = base[(size_t)i * CC];
        float ax = fabsf(x);
        float e  = expf(-ax);
        float inv = 1.f / (1.f + e);
        float p  = (x >= 0.f) ? inv : e * inv;   // sigmoid(x)
        s_sig += p;
        float sp = fmaxf(x, 0.f) + log1pf(e);    // softplus(x), stable
        s_foc += 0.75f * p * p * sp;             // t=0 focal term
      }
      atomicAdd(&probs_sum[b * CC + c], s_sig);
    }
    double v = (double)s_foc;
    for (int off = 32; off; off >>= 1) v += __shfl_xor(v, off, 64);
    if (lane == 0) s_rd[wv] = v;
    __syncthreads();
    if (tid == 0) atomicAdd(&accs[0], s_rd[0] + s_rd[1] + s_rd[2] + s_rd[3]);
  } else {
    // ---------- pass B: greedy assignment for one batch ----------
    int b = bid - ABLK;
    for (int q = tid; q < QQ; q += 256) {
      s_qx[q] = qcen[((size_t)b * QQ + q) * 2 + 0];
      s_qy[q] = qcen[((size_t)b * QQ + q) * 2 + 1];
    }
    for (int g = tid; g < GG; g += 256) {
      s_gx[g] = gtb[((size_t)b * GG + g) * 5 + 0];
      s_gy[g] = gtb[((size_t)b * GG + g) * 5 + 1];
    }
    __syncthreads();

    // min distance per GT (waves split g)
    for (int g = wv; g < GG; g += 4) {
      float gx = s_gx[g], gy = s_gy[g];
      float best = INFINITY;
      for (int k = 0; k < 15; ++k) {
        int q = lane + (k << 6);
        if (q < QQ) best = fminf(best, distf(gx, gy, s_qx[q], s_qy[q]));
      }
      for (int off = 32; off; off >>= 1) best = fminf(best, __shfl_xor(best, off, 64));
      if (lane == 0) s_ming[g] = best;
    }
    __syncthreads();

    // stable argsort rank (value, index)
    if (tid < GG) {
      float m = s_ming[tid];
      int r = 0;
      for (int j = 0; j < GG; ++j) {
        float mj = s_ming[j];
        r += (mj < m) || (mj == m && j < tid);
      }
      s_order[r] = tid;
    }
    __syncthreads();

    // greedy: each ordered GT takes nearest unused query
    unsigned used = 0;  // bit k covers q = tid + 256k
    for (int i = 0; i < GG; ++i) {
      int g = s_order[i];
      float gx = s_gx[g], gy = s_gy[g];
      unsigned long long best = ~0ULL;
      for (int k = 0; k < 4; ++k) {
        int q = tid + (k << 8);
        if (q < QQ && !((used >> k) & 1u)) {
          float d = distf(gx, gy, s_qx[q], s_qy[q]);
          unsigned long long pk =
              ((unsigned long long)__float_as_uint(d) << 32) | (unsigned)q;
          best = best < pk ? best : pk;
        }
      }
      for (int off = 32; off; off >>= 1) {
        unsigned long long o = __shfl_xor(best, off, 64);
        best = best < o ? best : o;
      }
      if (lane == 0) s_r64[wv] = best;
      __syncthreads();
      unsigned long long m01 = s_r64[0] < s_r64[1] ? s_r64[0] : s_r64[1];
      unsigned long long m23 = s_r64[2] < s_r64[3] ? s_r64[2] : s_r64[3];
      unsigned long long mw  = m01 < m23 ? m01 : m23;
      int qwin = (int)(unsigned)(mw & 0xffffffffu);
      if (tid == (qwin & 255)) used |= 1u << (qwin >> 8);
      if (tid == 0) s_qs[i] = qwin;
      __syncthreads();
    }

    // corrections: focal t=0 -> t=1 patch + smooth-L1 box loss (positives only)
    double dcls = 0.0, dbox = 0.0;
    if (tid < GG) {
      int g   = s_order[tid];
      int q   = s_qs[tid];
      int lab = gtl[b * GG + g];
      float x  = logits[((size_t)b * QQ + q) * CC + lab];
      float ax = fabsf(x);
      float e  = expf(-ax);
      float inv = 1.f / (1.f + e);
      float p  = (x >= 0.f) ? inv : e * inv;
      float sp = fmaxf(x, 0.f) + log1pf(e);          // softplus(x)
      float neg = 0.75f * p * p * sp;                // t=0 term (remove)
      float omp = 1.f - p;
      float pos = 0.25f * omp * omp * (sp - x);      // t=1 term (add)
      dcls = (double)pos - (double)neg;
      float bs = 0.f;
      for (int j = 0; j < 5; ++j) {
        float diff = boxes[((size_t)b * QQ + q) * 5 + j] -
                     gtb[((size_t)b * GG + g) * 5 + j];
        float ad = fabsf(diff);
        bs += (ad < 1.f) ? 0.5f * diff * diff : ad - 0.5f;
      }
      dbox = (double)bs;
    }
    for (int off = 32; off; off >>= 1) {
      dcls += __shfl_xor(dcls, off, 64);
      dbox += __shfl_xor(dbox, off, 64);
    }
    if (lane == 0) { s_rd[wv] = dcls; s_rd[4 + wv] = dbox; }
    __syncthreads();
    if (tid == 0) {
      atomicAdd(&accs[0], s_rd[0] + s_rd[1] + s_rd[2] + s_rd[3]);
      atomicAdd(&accs[1], s_rd[4] + s_rd[5] + s_rd[6] + s_rd[7]);
    }
  }
}

// hier: y_c = rowsum_c * x_c - (R x)_c ; hier_b = sum_c x_c y_c
__global__ __launch_bounds__(256) void hier_kernel(
    const float* __restrict__ Rm, const float* __restrict__ probs_sum,
    double* __restrict__ accs)
{
  __shared__ float s_x[HB * CC];   // 38.5 KB
  __shared__ double s_rd[4];
  const int tid = threadIdx.x, lane = tid & 63, wv = tid >> 6;
  const int b0 = blockIdx.y * HB;
  const float inv_q = 1.f / (float)QQ;
  for (int bb = 0; bb < HB; ++bb)
    for (int d = tid; d < CC; d += 256)
      s_x[bb * CC + d] = probs_sum[(b0 + bb) * CC + d] * inv_q;
  __syncthreads();

  int c = blockIdx.x * 4 + wv;
  double part = 0.0;
  if (c < CC) {
    float rs = 0.f;
    float dot[HB];
    #pragma unroll
    for (int bb = 0; bb < HB; ++bb) dot[bb] = 0.f;
    const float* row = Rm + (size_t)c * CC;
    for (int d = lane; d < CC; d += 64) {
      float r = row[d];
      rs += r;
      #pragma unroll
      for (int bb = 0; bb < HB; ++bb) dot[bb] += r * s_x[bb * CC + d];
    }
    for (int off = 32; off; off >>= 1) {
      rs += __shfl_xor(rs, off, 64);
      #pragma unroll
      for (int bb = 0; bb < HB; ++bb) dot[bb] += __shfl_xor(dot[bb], off, 64);
    }
    if (lane == 0) {
      for (int bb = 0; bb < HB; ++bb) {
        float xc = s_x[bb * CC + c];
        part += (double)xc * ((double)xc * (double)rs - (double)dot[bb]);
      }
    }
  }
  if (lane == 0) s_rd[wv] = part;
  __syncthreads();
  if (tid == 0) atomicAdd(&accs[2], s_rd[0] + s_rd[1] + s_rd[2] + s_rd[3]);
}

__global__ void finalize_kernel(const double* __restrict__ accs,
                                float* __restrict__ out)
{
  if (threadIdx.x == 0 && blockIdx.x == 0) {
    double cls  = accs[0] / (double)((size_t)BB * QQ * CC);
    double box  = accs[1] / 8000.0;   // sum(m)*5 = 16*100*5, all GTs assigned
    double hier = accs[2] / (double)BB;
    double total = 1.0 * cls + 5.0 * box + 0.1 * hier;
    out[0] = (float)total;
    out[1] = (float)cls;
    out[2] = (float)box;
    out[3] = (float)hier;
  }
}

extern "C" void kernel_launch(void* const* d_in, const int* in_sizes, int n_in,
                              void* d_out, int out_size, void* d_ws, size_t ws_size,
                              hipStream_t stream) {
  const float* logits = (const float*)d_in[0];
  const float* boxes  = (const float*)d_in[1];
  const float* qcen   = (const float*)d_in[2];
  const float* gtb    = (const float*)d_in[3];
  const int*   gtl    = (const int*)d_in[4];
  const float* relm   = (const float*)d_in[5];

  float*  probs_sum = (float*)d_ws;                  // BB*CC floats = 76,992 B
  double* accs      = (double*)((char*)d_ws + 80000); // 8B aligned

  hipMemsetAsync(d_ws, 0, 80000 + 4 * sizeof(double), stream);

  fused_main<<<ABLK + BB, 256, 0, stream>>>(logits, boxes, qcen, gtb, gtl,
                                            probs_sum, accs);
  hier_kernel<<<dim3((CC + 3) / 4, BB / HB), 256, 0, stream>>>(relm, probs_sum, accs);
  finalize_kernel<<<1, 64, 0, stream>>>(accs, (float*)d_out);
}

// Round 4
// 192.172 us; speedup vs baseline: 1.4749x; 1.4749x over previous
//
#include <hip/hip_runtime.h>
#include <math.h>

#define BB 16
#define QQ 900
#define CC 1203
#define GG 100

constexpr int CT   = 5;              // ceil(1203/256) c-tiles
constexpr int QCH  = 20;             // q chunks
constexpr int QPC  = QQ / QCH;       // 45 q per chunk
constexpr int GBLK = BB;             // 16 greedy blocks, dispatched first
constexpr int ABLK = CT * BB * QCH;  // 1600 streaming blocks

// fast sigmoid + softplus (errors ~1e-6 rel; final outputs are means with
// 0.69 abs tolerance, so native exp/log/rcp are safe)
__device__ __forceinline__ void sig_sp(float x, float& p, float& sp) {
  float ax = fabsf(x);
  float e  = __expf(-ax);
  float r  = __builtin_amdgcn_rcpf(1.f + e);
  p  = (x >= 0.f) ? r : 1.f - r;
  sp = fmaxf(x, 0.f) + __logf(1.f + e);
}

__global__ __launch_bounds__(256) void fused_main(
    const float* __restrict__ logits, const float* __restrict__ boxes,
    const float* __restrict__ qcen,  const float* __restrict__ gtb,
    const int* __restrict__ gtl, float* __restrict__ probs_sum,
    double* __restrict__ accs)
{
  __shared__ float s_gx[GG], s_gy[GG], s_ming[GG];
  __shared__ int s_ord[GG], s_qs[GG];
  __shared__ double s_rd[8];

  const int bid  = blockIdx.x;
  const int tid  = threadIdx.x;
  const int lane = tid & 63;
  const int wv   = tid >> 6;

  if (bid < GBLK) {
    // ================= greedy assignment, one batch per block =============
    // All 4 waves run the serial chain redundantly (identical deterministic
    // results) so __syncthreads stays legal; no cross-wave traffic inside
    // the 100-iteration loop.
    const int b = bid;
    // lane-contiguous query chunks: lanes 0-3 own 15 q's, lanes 4-63 own 14.
    // lane order == q order, so lowest-lane tie-break == lowest-q tie-break.
    const int cnt    = lane < 4 ? 15 : 14;
    const int qstart = lane < 4 ? lane * 15 : 60 + (lane - 4) * 14;
    float qx[15], qy[15];
    #pragma unroll
    for (int k = 0; k < 15; ++k) {
      int q = qstart + ((k < cnt) ? k : 0);
      float2 c2 = ((const float2*)qcen)[(size_t)b * QQ + q];
      qx[k] = (k < cnt) ? c2.x : 0.f;
      qy[k] = (k < cnt) ? c2.y : 0.f;
    }
    if (tid < GG) {
      s_gx[tid] = gtb[((size_t)b * GG + tid) * 5 + 0];
      s_gy[tid] = gtb[((size_t)b * GG + tid) * 5 + 1];
    }
    __syncthreads();

    // min squared-distance per GT (waves split the g range; squared distance
    // is order-equivalent to sqrt, near-tie perturbation ~1e-3 on outputs)
    for (int g = wv * 25; g < (wv + 1) * 25; ++g) {
      float bx = s_gx[g], by = s_gy[g];
      float bd = __builtin_inff();
      #pragma unroll
      for (int k = 0; k < 15; ++k) {
        float dx = bx - qx[k], dy = by - qy[k];
        float d  = fmaf(dy, dy, dx * dx);
        bd = fminf(bd, (k < cnt) ? d : __builtin_inff());
      }
      #pragma unroll
      for (int off = 32; off; off >>= 1) bd = fminf(bd, __shfl_xor(bd, off, 64));
      if (lane == 0) s_ming[g] = bd;
    }
    __syncthreads();

    // stable argsort rank (value, index)
    if (tid < GG) {
      float m = s_ming[tid];
      int r = 0;
      for (int j = 0; j < GG; ++j) {
        float mj = s_ming[j];
        r += (mj < m) || (mj == m && j < tid);
      }
      s_ord[r] = tid;
    }
    __syncthreads();

    // greedy chain: register-resident, shuffle+ballot only, no barriers
    unsigned used = 0;
    for (int i = 0; i < GG; ++i) {
      int g = s_ord[i];
      float bx = s_gx[g], by = s_gy[g];
      float bd = __builtin_inff();
      int bk = 0;
      #pragma unroll
      for (int k = 0; k < 15; ++k) {
        float dx = bx - qx[k], dy = by - qy[k];
        float d  = fmaf(dy, dy, dx * dx);
        bool ok = (k < cnt) && !((used >> k) & 1u);
        d = ok ? d : __builtin_inff();
        if (d < bd) { bd = d; bk = k; }   // strict < keeps lowest k
      }
      float wm = bd;
      #pragma unroll
      for (int off = 32; off; off >>= 1) wm = fminf(wm, __shfl_xor(wm, off, 64));
      unsigned long long ball = __ballot(bd == wm);
      int wl = __ffsll(ball) - 1;         // lowest lane == lowest q (chunks ascend)
      int wk = __shfl(bk, wl, 64);
      int qwin = (wl < 4 ? wl * 15 : 60 + (wl - 4) * 14) + wk;
      if (lane == wl) used |= 1u << bk;
      if (tid == 0) s_qs[i] = qwin;
    }
    __syncthreads();

    // corrections: focal t=0 -> t=1 patch + smooth-L1 box loss on positives
    double dcls = 0.0, dbox = 0.0;
    if (tid < GG) {
      int g   = s_ord[tid];
      int q   = s_qs[tid];
      int lab = gtl[b * GG + g];
      float x = logits[((size_t)b * QQ + q) * CC + lab];
      float p, sp; sig_sp(x, p, sp);
      float omp = 1.f - p;
      dcls = (double)(0.25f * omp * omp * (sp - x)) -
             (double)(0.75f * p * p * sp);
      float bs = 0.f;
      #pragma unroll
      for (int j = 0; j < 5; ++j) {
        float diff = boxes[((size_t)b * QQ + q) * 5 + j] -
                     gtb[((size_t)b * GG + g) * 5 + j];
        float ad = fabsf(diff);
        bs += (ad < 1.f) ? 0.5f * diff * diff : ad - 0.5f;
      }
      dbox = (double)bs;
    }
    #pragma unroll
    for (int off = 32; off; off >>= 1) {
      dcls += __shfl_xor(dcls, off, 64);
      dbox += __shfl_xor(dbox, off, 64);
    }
    if (lane == 0) { s_rd[wv] = dcls; s_rd[4 + wv] = dbox; }
    __syncthreads();
    if (tid == 0) {
      atomicAdd(&accs[0], s_rd[0] + s_rd[1] + s_rd[2] + s_rd[3]);
      atomicAdd(&accs[1], s_rd[4] + s_rd[5] + s_rd[6] + s_rd[7]);
    }
  } else {
    // ================= streaming: focal base + sigmoid row-sums ===========
    int sid = bid - GBLK;
    int ct = sid % CT;
    int b  = (sid / CT) % BB;
    int qk = sid / (CT * BB);
    int c  = ct * 256 + tid;
    float s_sig = 0.f, s_foc = 0.f;
    if (c < CC) {
      const float* base = logits + ((size_t)b * QQ + (size_t)qk * QPC) * CC + c;
      for (int i = 0; i < QPC; ++i) {
        float x = base[(size_t)i * CC];
        float p, sp; sig_sp(x, p, sp);
        s_sig += p;
        s_foc += 0.75f * p * p * sp;     // t=0 focal term
      }
      atomicAdd(&probs_sum[b * CC + c], s_sig);
    }
    double v = (double)s_foc;
    #pragma unroll
    for (int off = 32; off; off >>= 1) v += __shfl_xor(v, off, 64);
    if (lane == 0) s_rd[wv] = v;
    __syncthreads();
    if (tid == 0) atomicAdd(&accs[0], s_rd[0] + s_rd[1] + s_rd[2] + s_rd[3]);
  }
}

// hier: per row c of R: part_c = x_c * (x_c * rowsum_c - dot(R_c, x)) summed
// over 16 batches; R read exactly once.
__global__ __launch_bounds__(256) void hier_kernel(
    const float* __restrict__ Rm, const float* __restrict__ probs_sum,
    double* __restrict__ accs)
{
  __shared__ float s_x[BB * CC];   // 77 KB
  __shared__ double s_rd[4];
  const int tid = threadIdx.x, lane = tid & 63, wv = tid >> 6;
  const float inv_q = 1.f / (float)QQ;
  constexpr int N4 = BB * CC / 4;  // 19248/4, exact
  const float4* src4 = (const float4*)probs_sum;
  for (int i = tid; i < N4; i += 256) {
    float4 v = src4[i];
    s_x[i * 4 + 0] = v.x * inv_q;
    s_x[i * 4 + 1] = v.y * inv_q;
    s_x[i * 4 + 2] = v.z * inv_q;
    s_x[i * 4 + 3] = v.w * inv_q;
  }
  __syncthreads();

  int c = blockIdx.x * 4 + wv;
  double part = 0.0;
  if (c < CC) {
    const float* row = Rm + (size_t)c * CC;
    float rs = 0.f, dot[BB];
    #pragma unroll
    for (int bb = 0; bb < BB; ++bb) dot[bb] = 0.f;
    for (int d = lane; d < CC; d += 64) {
      float r = row[d];
      rs += r;
      #pragma unroll
      for (int bb = 0; bb < BB; ++bb) dot[bb] = fmaf(r, s_x[bb * CC + d], dot[bb]);
    }
    #pragma unroll
    for (int off = 32; off; off >>= 1) {
      rs += __shfl_xor(rs, off, 64);
      #pragma unroll
      for (int bb = 0; bb < BB; ++bb) dot[bb] += __shfl_xor(dot[bb], off, 64);
    }
    if (lane == 0) {
      #pragma unroll
      for (int bb = 0; bb < BB; ++bb) {
        float xc = s_x[bb * CC + c];
        part += (double)xc * ((double)xc * (double)rs - (double)dot[bb]);
      }
    }
  }
  if (lane == 0) s_rd[wv] = part;
  __syncthreads();
  if (tid == 0) atomicAdd(&accs[2], s_rd[0] + s_rd[1] + s_rd[2] + s_rd[3]);
}

__global__ void finalize_kernel(const double* __restrict__ accs,
                                float* __restrict__ out)
{
  if (threadIdx.x == 0 && blockIdx.x == 0) {
    double cls  = accs[0] / (double)((size_t)BB * QQ * CC);
    double box  = accs[1] / 8000.0;   // sum(m)*5 = 16*100*5, all GTs assigned
    double hier = accs[2] / (double)BB;
    double total = 1.0 * cls + 5.0 * box + 0.1 * hier;
    out[0] = (float)total;
    out[1] = (float)cls;
    out[2] = (float)box;
    out[3] = (float)hier;
  }
}

extern "C" void kernel_launch(void* const* d_in, const int* in_sizes, int n_in,
                              void* d_out, int out_size, void* d_ws, size_t ws_size,
                              hipStream_t stream) {
  const float* logits = (const float*)d_in[0];
  const float* boxes  = (const float*)d_in[1];
  const float* qcen   = (const float*)d_in[2];
  const float* gtb    = (const float*)d_in[3];
  const int*   gtl    = (const int*)d_in[4];
  const float* relm   = (const float*)d_in[5];

  float*  probs_sum = (float*)d_ws;                   // 16*1203 floats
  double* accs      = (double*)((char*)d_ws + 80000); // 8B aligned

  hipMemsetAsync(d_ws, 0, 80000 + 4 * sizeof(double), stream);

  fused_main<<<GBLK + ABLK, 256, 0, stream>>>(logits, boxes, qcen, gtb, gtl,
                                              probs_sum, accs);
  hier_kernel<<<(CC + 3) / 4, 256, 0, stream>>>(relm, probs_sum, accs);
  finalize_kernel<<<1, 64, 0, stream>>>(accs, (float*)d_out);
}

// Round 7
// 178.709 us; speedup vs baseline: 1.5860x; 1.0753x over previous
//
#include <hip/hip_runtime.h>
#include <math.h>

#define BB 16
#define QQ 900
#define CC 1203
#define GG 100

constexpr int CT   = 5;              // ceil(1203/256) c-tiles
constexpr int QCH  = 20;             // q chunks
constexpr int QPC  = QQ / QCH;       // 45 q per chunk
constexpr int GBLK = BB;             // 16 greedy blocks, dispatched first
constexpr int ABLK = CT * BB * QCH;  // 1600 streaming blocks

// fast sigmoid + softplus (errors ~1e-6 rel; outputs are means with 0.69 abs
// tolerance, so native exp/log/rcp are safe)
__device__ __forceinline__ void sig_sp(float x, float& p, float& sp) {
  float ax = fabsf(x);
  float e  = __expf(-ax);
  float r  = __builtin_amdgcn_rcpf(1.f + e);
  p  = (x >= 0.f) ? r : 1.f - r;
  sp = fmaxf(x, 0.f) + __logf(1.f + e);
}

// wave64 f32 min via DPP (VALU-only, ~6 dependent ops vs 6 ds_swizzle
// round-trips). Valid result in lane 63; OOB/unwritten lanes inherit +inf so
// the running min is unaffected. row_shr:N = 0x110|N, bcast15=0x142 (rows 1,3),
// bcast31=0x143 (rows 2,3).
__device__ __forceinline__ float dpp_min64(float x) {
  const int INFB = 0x7f800000;
  int xi = __float_as_int(x), t;
  t  = __builtin_amdgcn_update_dpp(INFB, xi, 0x111, 0xF, 0xF, false);
  xi = __float_as_int(fminf(__int_as_float(xi), __int_as_float(t)));
  t  = __builtin_amdgcn_update_dpp(INFB, xi, 0x112, 0xF, 0xF, false);
  xi = __float_as_int(fminf(__int_as_float(xi), __int_as_float(t)));
  t  = __builtin_amdgcn_update_dpp(INFB, xi, 0x114, 0xF, 0xF, false);
  xi = __float_as_int(fminf(__int_as_float(xi), __int_as_float(t)));
  t  = __builtin_amdgcn_update_dpp(INFB, xi, 0x118, 0xF, 0xF, false);
  xi = __float_as_int(fminf(__int_as_float(xi), __int_as_float(t)));
  t  = __builtin_amdgcn_update_dpp(INFB, xi, 0x142, 0xA, 0xF, false);
  xi = __float_as_int(fminf(__int_as_float(xi), __int_as_float(t)));
  t  = __builtin_amdgcn_update_dpp(INFB, xi, 0x143, 0xC, 0xF, false);
  xi = __float_as_int(fminf(__int_as_float(xi), __int_as_float(t)));
  return __int_as_float(xi);
}

__global__ __launch_bounds__(256) void fused_main(
    const float* __restrict__ logits, const float* __restrict__ boxes,
    const float* __restrict__ qcen,  const float* __restrict__ gtb,
    const int* __restrict__ gtl, float* __restrict__ probs_sum,
    double* __restrict__ accs)
{
  __shared__ float s_gx[GG], s_gy[GG], s_ming[GG];
  __shared__ int s_ord[GG], s_qs[GG];
  __shared__ double s_rd[8];

  const int bid  = blockIdx.x;
  const int tid  = threadIdx.x;
  const int lane = tid & 63;
  const int wv   = tid >> 6;
  const float FINF = __builtin_inff();

  if (bid < GBLK) {
    // ================= greedy assignment, one batch per block =============
    // All 4 waves run the serial chain redundantly (identical deterministic
    // results) so __syncthreads stays legal; no cross-wave traffic inside
    // the 100-iteration loop.
    const int b = bid;
    // lane-contiguous query chunks: lanes 0-3 own 15 q's, lanes 4-63 own 14.
    // lane order == q order, so lowest-lane tie-break == lowest-q tie-break.
    const int cnt    = lane < 4 ? 15 : 14;
    const int qstart = lane < 4 ? lane * 15 : 60 + (lane - 4) * 14;
    float qx[15], qy[15];
    #pragma unroll
    for (int k = 0; k < 15; ++k) {
      int q = qstart + ((k < cnt) ? k : 0);
      float2 c2 = ((const float2*)qcen)[(size_t)b * QQ + q];
      qx[k] = (k < cnt) ? c2.x : 0.f;
      qy[k] = (k < cnt) ? c2.y : 0.f;
    }
    if (tid < GG) {
      s_gx[tid] = gtb[((size_t)b * GG + tid) * 5 + 0];
      s_gy[tid] = gtb[((size_t)b * GG + tid) * 5 + 1];
    }
    __syncthreads();

    // min squared-distance per GT (waves split g; squared distance is
    // order-equivalent to sqrt)
    for (int g = wv * 25; g < (wv + 1) * 25; ++g) {
      float bx = s_gx[g], by = s_gy[g];
      float bd = FINF;
      #pragma unroll
      for (int k = 0; k < 15; ++k) {
        float dx = bx - qx[k], dy = by - qy[k];
        float d  = fmaf(dy, dy, dx * dx);
        bd = fminf(bd, (k < cnt) ? d : FINF);
      }
      float m = dpp_min64(bd);
      if (lane == 63) s_ming[g] = m;
    }
    __syncthreads();

    // stable argsort rank (value, index)
    if (tid < GG) {
      float m = s_ming[tid];
      int r = 0;
      for (int j = 0; j < GG; ++j) {
        float mj = s_ming[j];
        r += (mj < m) || (mj == m && j < tid);
      }
      s_ord[r] = tid;
    }
    __syncthreads();

    // greedy chain: register-resident; DPP min + ballot + readlane per step
    unsigned used = 0;
    for (int i = 0; i < GG; ++i) {
      int g = s_ord[i];
      float bx = s_gx[g], by = s_gy[g];
      float bd = FINF;
      int bk = 0;
      #pragma unroll
      for (int k = 0; k < 15; ++k) {
        float dx = bx - qx[k], dy = by - qy[k];
        float d  = fmaf(dy, dy, dx * dx);
        bool ok = (k < cnt) && !((used >> k) & 1u);
        d = ok ? d : FINF;
        if (d < bd) { bd = d; bk = k; }   // strict < keeps lowest k
      }
      float wm = dpp_min64(bd);
      wm = __int_as_float(__builtin_amdgcn_readlane(__float_as_int(wm), 63));
      unsigned long long ball = __ballot(bd == wm);
      int wl = __ffsll((long long)ball) - 1;  // lowest lane == lowest q
      int wk = __builtin_amdgcn_readlane(bk, wl);
      int qwin = (wl < 4 ? wl * 15 : 60 + (wl - 4) * 14) + wk;
      if (lane == wl) used |= 1u << wk;
      if (tid == 0) s_qs[i] = qwin;
    }
    __syncthreads();

    // corrections: focal t=0 -> t=1 patch + smooth-L1 box loss on positives
    double dcls = 0.0, dbox = 0.0;
    if (tid < GG) {
      int g   = s_ord[tid];
      int q   = s_qs[tid];
      int lab = gtl[b * GG + g];
      float x = logits[((size_t)b * QQ + q) * CC + lab];
      float p, sp; sig_sp(x, p, sp);
      float omp = 1.f - p;
      dcls = (double)(0.25f * omp * omp * (sp - x)) -
             (double)(0.75f * p * p * sp);
      float bs = 0.f;
      #pragma unroll
      for (int j = 0; j < 5; ++j) {
        float diff = boxes[((size_t)b * QQ + q) * 5 + j] -
                     gtb[((size_t)b * GG + g) * 5 + j];
        float ad = fabsf(diff);
        bs += (ad < 1.f) ? 0.5f * diff * diff : ad - 0.5f;
      }
      dbox = (double)bs;
    }
    #pragma unroll
    for (int off = 32; off; off >>= 1) {
      dcls += __shfl_xor(dcls, off, 64);
      dbox += __shfl_xor(dbox, off, 64);
    }
    if (lane == 0) { s_rd[wv] = dcls; s_rd[4 + wv] = dbox; }
    __syncthreads();
    if (tid == 0) {
      atomicAdd(&accs[0], s_rd[0] + s_rd[1] + s_rd[2] + s_rd[3]);
      atomicAdd(&accs[1], s_rd[4] + s_rd[5] + s_rd[6] + s_rd[7]);
    }
  } else {
    // ================= streaming: focal base + sigmoid row-sums ===========
    int sid = bid - GBLK;
    int ct = sid % CT;
    int b  = (sid / CT) % BB;
    int qk = sid / (CT * BB);
    int c  = ct * 256 + tid;
    float s_sig = 0.f, s_foc = 0.f;
    if (c < CC) {
      const float* base = logits + ((size_t)b * QQ + (size_t)qk * QPC) * CC + c;
      // group-of-5 unroll: 5 independent loads in flight per group (MLP)
      for (int i0 = 0; i0 < QPC; i0 += 5) {
        float xs[5];
        #pragma unroll
        for (int u = 0; u < 5; ++u) xs[u] = base[(size_t)(i0 + u) * CC];
        #pragma unroll
        for (int u = 0; u < 5; ++u) {
          float p, sp; sig_sp(xs[u], p, sp);
          s_sig += p;
          s_foc += 0.75f * p * p * sp;   // t=0 focal term
        }
      }
      atomicAdd(&probs_sum[b * CC + c], s_sig);
    }
    double v = (double)s_foc;
    #pragma unroll
    for (int off = 32; off; off >>= 1) v += __shfl_xor(v, off, 64);
    if (lane == 0) s_rd[wv] = v;
    __syncthreads();
    if (tid == 0) atomicAdd(&accs[0], s_rd[0] + s_rd[1] + s_rd[2] + s_rd[3]);
  }
}

// hier: per row c of R: part_c = x_c * (x_c * rowsum_c - dot(R_c, x)) summed
// over 16 batches; R read exactly once.
__global__ __launch_bounds__(256) void hier_kernel(
    const float* __restrict__ Rm, const float* __restrict__ probs_sum,
    double* __restrict__ accs)
{
  __shared__ float s_x[BB * CC];   // 77 KB
  __shared__ double s_rd[4];
  const int tid = threadIdx.x, lane = tid & 63, wv = tid >> 6;
  const float inv_q = 1.f / (float)QQ;
  constexpr int N4 = BB * CC / 4;  // 19248/4, exact
  const float4* src4 = (const float4*)probs_sum;
  for (int i = tid; i < N4; i += 256) {
    float4 v = src4[i];
    s_x[i * 4 + 0] = v.x * inv_q;
    s_x[i * 4 + 1] = v.y * inv_q;
    s_x[i * 4 + 2] = v.z * inv_q;
    s_x[i * 4 + 3] = v.w * inv_q;
  }
  __syncthreads();

  int c = blockIdx.x * 4 + wv;
  double part = 0.0;
  if (c < CC) {
    const float* row = Rm + (size_t)c * CC;
    float rs = 0.f, dot[BB];
    #pragma unroll
    for (int bb = 0; bb < BB; ++bb) dot[bb] = 0.f;
    for (int d = lane; d < CC; d += 64) {
      float r = row[d];
      rs += r;
      #pragma unroll
      for (int bb = 0; bb < BB; ++bb) dot[bb] = fmaf(r, s_x[bb * CC + d], dot[bb]);
    }
    #pragma unroll
    for (int off = 32; off; off >>= 1) {
      rs += __shfl_xor(rs, off, 64);
      #pragma unroll
      for (int bb = 0; bb < BB; ++bb) dot[bb] += __shfl_xor(dot[bb], off, 64);
    }
    if (lane == 0) {
      #pragma unroll
      for (int bb = 0; bb < BB; ++bb) {
        float xc = s_x[bb * CC + c];
        part += (double)xc * ((double)xc * (double)rs - (double)dot[bb]);
      }
    }
  }
  if (lane == 0) s_rd[wv] = part;
  __syncthreads();
  if (tid == 0) atomicAdd(&accs[2], s_rd[0] + s_rd[1] + s_rd[2] + s_rd[3]);
}

__global__ void finalize_kernel(const double* __restrict__ accs,
                                float* __restrict__ out)
{
  if (threadIdx.x == 0 && blockIdx.x == 0) {
    double cls  = accs[0] / (double)((size_t)BB * QQ * CC);
    double box  = accs[1] / 8000.0;   // sum(m)*5 = 16*100*5, all GTs assigned
    double hier = accs[2] / (double)BB;
    double total = 1.0 * cls + 5.0 * box + 0.1 * hier;
    out[0] = (float)total;
    out[1] = (float)cls;
    out[2] = (float)box;
    out[3] = (float)hier;
  }
}

extern "C" void kernel_launch(void* const* d_in, const int* in_sizes, int n_in,
                              void* d_out, int out_size, void* d_ws, size_t ws_size,
                              hipStream_t stream) {
  const float* logits = (const float*)d_in[0];
  const float* boxes  = (const float*)d_in[1];
  const float* qcen   = (const float*)d_in[2];
  const float* gtb    = (const float*)d_in[3];
  const int*   gtl    = (const int*)d_in[4];
  const float* relm   = (const float*)d_in[5];

  float*  probs_sum = (float*)d_ws;                   // 16*1203 floats
  double* accs      = (double*)((char*)d_ws + 80000); // 8B aligned

  hipMemsetAsync(d_ws, 0, 80000 + 4 * sizeof(double), stream);

  fused_main<<<GBLK + ABLK, 256, 0, stream>>>(logits, boxes, qcen, gtb, gtl,
                                              probs_sum, accs);
  hier_kernel<<<(CC + 3) / 4, 256, 0, stream>>>(relm, probs_sum, accs);
  finalize_kernel<<<1, 64, 0, stream>>>(accs, (float*)d_out);
}

// Round 11
// 157.768 us; speedup vs baseline: 1.7965x; 1.1327x over previous
//
#include <hip/hip_runtime.h>
#include <math.h>

#define BB 16
#define QQ 900
#define CC 1203
#define GG 100

constexpr int CT   = 5;              // ceil(1203/256) c-tiles
constexpr int QCH  = 20;             // q chunks
constexpr int QPC  = QQ / QCH;       // 45 q per chunk
constexpr int GBLK = BB;             // 16 greedy blocks, dispatched first
constexpr int ABLK = CT * BB * QCH;  // 1600 streaming blocks

// fast sigmoid + softplus (errors ~1e-6 rel; outputs are means with 0.69 abs
// tolerance, so native exp/log/rcp are safe)
__device__ __forceinline__ void sig_sp(float x, float& p, float& sp) {
  float ax = fabsf(x);
  float e  = __expf(-ax);
  float r  = __builtin_amdgcn_rcpf(1.f + e);
  p  = (x >= 0.f) ? r : 1.f - r;
  sp = fmaxf(x, 0.f) + __logf(1.f + e);
}

// wave64 f32 min via DPP (validated on HW in R7: absmax 0.0).
__device__ __forceinline__ float dpp_min64(float x) {
  const int INFB = 0x7f800000;
  int xi = __float_as_int(x), t;
  t  = __builtin_amdgcn_update_dpp(INFB, xi, 0x111, 0xF, 0xF, false);
  xi = __float_as_int(fminf(__int_as_float(xi), __int_as_float(t)));
  t  = __builtin_amdgcn_update_dpp(INFB, xi, 0x112, 0xF, 0xF, false);
  xi = __float_as_int(fminf(__int_as_float(xi), __int_as_float(t)));
  t  = __builtin_amdgcn_update_dpp(INFB, xi, 0x114, 0xF, 0xF, false);
  xi = __float_as_int(fminf(__int_as_float(xi), __int_as_float(t)));
  t  = __builtin_amdgcn_update_dpp(INFB, xi, 0x118, 0xF, 0xF, false);
  xi = __float_as_int(fminf(__int_as_float(xi), __int_as_float(t)));
  t  = __builtin_amdgcn_update_dpp(INFB, xi, 0x142, 0xA, 0xF, false);
  xi = __float_as_int(fminf(__int_as_float(xi), __int_as_float(t)));
  t  = __builtin_amdgcn_update_dpp(INFB, xi, 0x143, 0xC, 0xF, false);
  xi = __float_as_int(fminf(__int_as_float(xi), __int_as_float(t)));
  return __int_as_float(xi);
}

// wave64 u32 min via DPP, same lane pattern; shifted-in/masked lanes get
// UINT_MAX so the running min is unaffected.
__device__ __forceinline__ unsigned dpp_umin64(unsigned x) {
  unsigned t;
  t = (unsigned)__builtin_amdgcn_update_dpp((int)0xFFFFFFFFu, (int)x, 0x111, 0xF, 0xF, false);
  x = x < t ? x : t;
  t = (unsigned)__builtin_amdgcn_update_dpp((int)0xFFFFFFFFu, (int)x, 0x112, 0xF, 0xF, false);
  x = x < t ? x : t;
  t = (unsigned)__builtin_amdgcn_update_dpp((int)0xFFFFFFFFu, (int)x, 0x114, 0xF, 0xF, false);
  x = x < t ? x : t;
  t = (unsigned)__builtin_amdgcn_update_dpp((int)0xFFFFFFFFu, (int)x, 0x118, 0xF, 0xF, false);
  x = x < t ? x : t;
  t = (unsigned)__builtin_amdgcn_update_dpp((int)0xFFFFFFFFu, (int)x, 0x142, 0xA, 0xF, false);
  x = x < t ? x : t;
  t = (unsigned)__builtin_amdgcn_update_dpp((int)0xFFFFFFFFu, (int)x, 0x143, 0xC, 0xF, false);
  x = x < t ? x : t;
  return x;
}

__global__ __launch_bounds__(256) void fused_main(
    const float* __restrict__ logits, const float* __restrict__ boxes,
    const float* __restrict__ qcen,  const float* __restrict__ gtb,
    const int* __restrict__ gtl, float* __restrict__ probs_sum,
    double* __restrict__ accs)
{
  __shared__ float s_gx[GG], s_gy[GG], s_ming[GG];
  __shared__ float s_ogx[GG], s_ogy[GG];
  __shared__ int s_ord[GG], s_qs[GG];
  __shared__ double s_rd[8];

  const int bid  = blockIdx.x;
  const int tid  = threadIdx.x;
  const int lane = tid & 63;
  const int wv   = tid >> 6;
  const float FINF = __builtin_inff();

  if (bid < GBLK) {
    // ================= greedy assignment, one batch per block =============
    // All 4 waves run the serial chain redundantly (identical deterministic
    // results); no cross-wave traffic inside the 100-iteration loop.
    const int b = bid;
    // lane-contiguous query chunks: lanes 0-3 own 15 q's, lanes 4-63 own 14.
    // lane order == q order, so lowest-lane tie-break == lowest-q tie-break.
    const int cnt    = lane < 4 ? 15 : 14;
    const int qstart = lane < 4 ? lane * 15 : 60 + (lane - 4) * 14;
    float qx[15], qy[15];   // invalid slots carry +inf -> dist=+inf, never win
    #pragma unroll
    for (int k = 0; k < 15; ++k) {
      int q = qstart + ((k < cnt) ? k : 0);
      float2 c2 = ((const float2*)qcen)[(size_t)b * QQ + q];
      qx[k] = (k < cnt) ? c2.x : FINF;
      qy[k] = (k < cnt) ? c2.y : 0.f;
    }
    if (tid < GG) {
      s_gx[tid] = gtb[((size_t)b * GG + tid) * 5 + 0];
      s_gy[tid] = gtb[((size_t)b * GG + tid) * 5 + 1];
    }
    __syncthreads();

    // min squared-distance per GT (waves split g; squared distance is
    // order-equivalent to sqrt). f32 min tree (depth 4) + DPP reduce.
    for (int g = wv * 25; g < (wv + 1) * 25; ++g) {
      float bx = s_gx[g], by = s_gy[g];
      float d[16];
      d[15] = FINF;
      #pragma unroll
      for (int k = 0; k < 15; ++k) {
        float dx = bx - qx[k], dy = by - qy[k];
        d[k] = fmaf(dy, dy, dx * dx);
      }
      #pragma unroll
      for (int s = 8; s >= 1; s >>= 1)
        #pragma unroll
        for (int k = 0; k < 8; ++k)
          if (k < s) d[k] = fminf(d[k], d[k + s]);
      float m = dpp_min64(d[0]);
      if (lane == 63) s_ming[g] = m;
    }
    __syncthreads();

    // stable argsort rank (value, index)
    if (tid < GG) {
      float m = s_ming[tid];
      int r = 0;
      for (int j = 0; j < GG; ++j) {
        float mj = s_ming[j];
        r += (mj < m) || (mj == m && j < tid);
      }
      s_ord[r] = tid;
    }
    __syncthreads();
    // ordered coords, directly indexable by iteration (kills per-iter
    // s_ord -> s_gx dependent-LDS chain)
    if (tid < GG) {
      int g = s_ord[tid];
      s_ogx[tid] = s_gx[g];
      s_ogy[tid] = s_gy[g];
    }
    __syncthreads();

    // greedy chain: register-resident; packed u32 min tree + DPP + ballot.
    // pk = (d_bits & ~15) | k : uint order == float order (d >= 0); in-lane
    // ties pick lowest k, cross-lane ballot picks lowest lane == lowest q.
    // Winner's slot is poisoned (qx=inf) instead of per-iter used-masking.
    float bx = s_ogx[0], by = s_ogy[0];
    for (int i = 0; i < GG; ++i) {
      int inext = (i + 1 < GG) ? i + 1 : i;
      float nbx = s_ogx[inext], nby = s_ogy[inext];   // prefetch, hides LDS lat
      unsigned p[16];
      p[15] = 0xFFFFFFFFu;
      #pragma unroll
      for (int k = 0; k < 15; ++k) {
        float dx = bx - qx[k], dy = by - qy[k];
        float dd = fmaf(dy, dy, dx * dx);
        p[k] = (__float_as_uint(dd) & 0xFFFFFFF0u) | (unsigned)k;
      }
      #pragma unroll
      for (int s = 8; s >= 1; s >>= 1)
        #pragma unroll
        for (int k = 0; k < 8; ++k)
          if (k < s) p[k] = p[k] < p[k + s] ? p[k] : p[k + s];
      unsigned wm = dpp_umin64(p[0]);
      wm = (unsigned)__builtin_amdgcn_readlane((int)wm, 63);
      unsigned long long ball = __ballot(p[0] == wm);
      int wl = __ffsll((long long)ball) - 1;  // lowest lane == lowest q
      int wk = (int)(wm & 15u);
      int qwin = (wl < 4 ? wl * 15 : 60 + (wl - 4) * 14) + wk;
      if (tid == 0) s_qs[i] = qwin;
      bool meW = (lane == wl);
      #pragma unroll
      for (int k = 0; k < 15; ++k)
        if (k == wk) qx[k] = meW ? FINF : qx[k];   // wk wave-uniform: static idx
      bx = nbx; by = nby;
    }
    __syncthreads();

    // corrections: focal t=0 -> t=1 patch + smooth-L1 box loss on positives
    double dcls = 0.0, dbox = 0.0;
    if (tid < GG) {
      int g   = s_ord[tid];
      int q   = s_qs[tid];
      int lab = gtl[b * GG + g];
      float x = logits[((size_t)b * QQ + q) * CC + lab];
      float p, sp; sig_sp(x, p, sp);
      float omp = 1.f - p;
      dcls = (double)(0.25f * omp * omp * (sp - x)) -
             (double)(0.75f * p * p * sp);
      float bs = 0.f;
      #pragma unroll
      for (int j = 0; j < 5; ++j) {
        float diff = boxes[((size_t)b * QQ + q) * 5 + j] -
                     gtb[((size_t)b * GG + g) * 5 + j];
        float ad = fabsf(diff);
        bs += (ad < 1.f) ? 0.5f * diff * diff : ad - 0.5f;
      }
      dbox = (double)bs;
    }
    #pragma unroll
    for (int off = 32; off; off >>= 1) {
      dcls += __shfl_xor(dcls, off, 64);
      dbox += __shfl_xor(dbox, off, 64);
    }
    if (lane == 0) { s_rd[wv] = dcls; s_rd[4 + wv] = dbox; }
    __syncthreads();
    if (tid == 0) {
      atomicAdd(&accs[0], s_rd[0] + s_rd[1] + s_rd[2] + s_rd[3]);
      atomicAdd(&accs[1], s_rd[4] + s_rd[5] + s_rd[6] + s_rd[7]);
    }
  } else {
    // ================= streaming: focal base + sigmoid row-sums ===========
    int sid = bid - GBLK;
    int ct = sid % CT;
    int b  = (sid / CT) % BB;
    int qk = sid / (CT * BB);
    int c  = ct * 256 + tid;
    float s_sig = 0.f, s_foc = 0.f;
    if (c < CC) {
      const float* base = logits + ((size_t)b * QQ + (size_t)qk * QPC) * CC + c;
      // group-of-5 unroll: 5 independent loads in flight per group (MLP)
      for (int i0 = 0; i0 < QPC; i0 += 5) {
        float xs[5];
        #pragma unroll
        for (int u = 0; u < 5; ++u) xs[u] = base[(size_t)(i0 + u) * CC];
        #pragma unroll
        for (int u = 0; u < 5; ++u) {
          float p, sp; sig_sp(xs[u], p, sp);
          s_sig += p;
          s_foc += 0.75f * p * p * sp;   // t=0 focal term
        }
      }
      atomicAdd(&probs_sum[b * CC + c], s_sig);
    }
    double v = (double)s_foc;
    #pragma unroll
    for (int off = 32; off; off >>= 1) v += __shfl_xor(v, off, 64);
    if (lane == 0) s_rd[wv] = v;
    __syncthreads();
    if (tid == 0) atomicAdd(&accs[0], s_rd[0] + s_rd[1] + s_rd[2] + s_rd[3]);
  }
}

// hier: per row c of R: part_c = x_c * (x_c * rowsum_c - dot(R_c, x)) summed
// over 16 batches; R read exactly once.
__global__ __launch_bounds__(256) void hier_kernel(
    const float* __restrict__ Rm, const float* __restrict__ probs_sum,
    double* __restrict__ accs)
{
  __shared__ float s_x[BB * CC];   // 77 KB
  __shared__ double s_rd[4];
  const int tid = threadIdx.x, lane = tid & 63, wv = tid >> 6;
  const float inv_q = 1.f / (float)QQ;
  constexpr int N4 = BB * CC / 4;  // 19248/4, exact
  const float4* src4 = (const float4*)probs_sum;
  for (int i = tid; i < N4; i += 256) {
    float4 v = src4[i];
    s_x[i * 4 + 0] = v.x * inv_q;
    s_x[i * 4 + 1] = v.y * inv_q;
    s_x[i * 4 + 2] = v.z * inv_q;
    s_x[i * 4 + 3] = v.w * inv_q;
  }
  __syncthreads();

  int c = blockIdx.x * 4 + wv;
  double part = 0.0;
  if (c < CC) {
    const float* row = Rm + (size_t)c * CC;
    float rs = 0.f, dot[BB];
    #pragma unroll
    for (int bb = 0; bb < BB; ++bb) dot[bb] = 0.f;
    for (int d = lane; d < CC; d += 64) {
      float r = row[d];
      rs += r;
      #pragma unroll
      for (int bb = 0; bb < BB; ++bb) dot[bb] = fmaf(r, s_x[bb * CC + d], dot[bb]);
    }
    #pragma unroll
    for (int off = 32; off; off >>= 1) {
      rs += __shfl_xor(rs, off, 64);
      #pragma unroll
      for (int bb = 0; bb < BB; ++bb) dot[bb] += __shfl_xor(dot[bb], off, 64);
    }
    if (lane == 0) {
      #pragma unroll
      for (int bb = 0; bb < BB; ++bb) {
        float xc = s_x[bb * CC + c];
        part += (double)xc * ((double)xc * (double)rs - (double)dot[bb]);
      }
    }
  }
  if (lane == 0) s_rd[wv] = part;
  __syncthreads();
  if (tid == 0) atomicAdd(&accs[2], s_rd[0] + s_rd[1] + s_rd[2] + s_rd[3]);
}

__global__ void finalize_kernel(const double* __restrict__ accs,
                                float* __restrict__ out)
{
  if (threadIdx.x == 0 && blockIdx.x == 0) {
    double cls  = accs[0] / (double)((size_t)BB * QQ * CC);
    double box  = accs[1] / 8000.0;   // sum(m)*5 = 16*100*5, all GTs assigned
    double hier = accs[2] / (double)BB;
    double total = 1.0 * cls + 5.0 * box + 0.1 * hier;
    out[0] = (float)total;
    out[1] = (float)cls;
    out[2] = (float)box;
    out[3] = (float)hier;
  }
}

extern "C" void kernel_launch(void* const* d_in, const int* in_sizes, int n_in,
                              void* d_out, int out_size, void* d_ws, size_t ws_size,
                              hipStream_t stream) {
  const float* logits = (const float*)d_in[0];
  const float* boxes  = (const float*)d_in[1];
  const float* qcen   = (const float*)d_in[2];
  const float* gtb    = (const float*)d_in[3];
  const int*   gtl    = (const int*)d_in[4];
  const float* relm   = (const float*)d_in[5];

  float*  probs_sum = (float*)d_ws;                   // 16*1203 floats
  double* accs      = (double*)((char*)d_ws + 80000); // 8B aligned

  hipMemsetAsync(d_ws, 0, 80000 + 4 * sizeof(double), stream);

  fused_main<<<GBLK + ABLK, 256, 0, stream>>>(logits, boxes, qcen, gtb, gtl,
                                              probs_sum, accs);
  hier_kernel<<<(CC + 3) / 4, 256, 0, stream>>>(relm, probs_sum, accs);
  finalize_kernel<<<1, 64, 0, stream>>>(accs, (float*)d_out);
}

// Round 12
// 139.678 us; speedup vs baseline: 2.0292x; 1.1295x over previous
//
#include <hip/hip_runtime.h>
#include <math.h>

#define BB 16
#define QQ 900
#define CC 1203
#define GG 100

constexpr int CT   = 5;              // ceil(1203/256) c-tiles
constexpr int QCH  = 20;             // q chunks
constexpr int QPC  = QQ / QCH;       // 45 q per chunk
constexpr int GBLK = BB;             // 16 greedy blocks, dispatched first
constexpr int ABLK = CT * BB * QCH;  // 1600 streaming blocks

// fast sigmoid + softplus (errors ~1e-6 rel; outputs are means with 0.69 abs
// tolerance, so native exp/log/rcp are safe)
__device__ __forceinline__ void sig_sp(float x, float& p, float& sp) {
  float ax = fabsf(x);
  float e  = __expf(-ax);
  float r  = __builtin_amdgcn_rcpf(1.f + e);
  p  = (x >= 0.f) ? r : 1.f - r;
  sp = fmaxf(x, 0.f) + __logf(1.f + e);
}

// wave64 u32 min via DPP (validated on HW in R11: absmax 0.0); shifted-in
// lanes get UINT_MAX so the running min is unaffected.
__device__ __forceinline__ unsigned dpp_umin64(unsigned x) {
  unsigned t;
  t = (unsigned)__builtin_amdgcn_update_dpp((int)0xFFFFFFFFu, (int)x, 0x111, 0xF, 0xF, false);
  x = x < t ? x : t;
  t = (unsigned)__builtin_amdgcn_update_dpp((int)0xFFFFFFFFu, (int)x, 0x112, 0xF, 0xF, false);
  x = x < t ? x : t;
  t = (unsigned)__builtin_amdgcn_update_dpp((int)0xFFFFFFFFu, (int)x, 0x114, 0xF, 0xF, false);
  x = x < t ? x : t;
  t = (unsigned)__builtin_amdgcn_update_dpp((int)0xFFFFFFFFu, (int)x, 0x118, 0xF, 0xF, false);
  x = x < t ? x : t;
  t = (unsigned)__builtin_amdgcn_update_dpp((int)0xFFFFFFFFu, (int)x, 0x142, 0xA, 0xF, false);
  x = x < t ? x : t;
  t = (unsigned)__builtin_amdgcn_update_dpp((int)0xFFFFFFFFu, (int)x, 0x143, 0xC, 0xF, false);
  x = x < t ? x : t;
  return x;
}

__global__ __launch_bounds__(256) void fused_main(
    const float* __restrict__ logits, const float* __restrict__ boxes,
    const float* __restrict__ qcen,  const float* __restrict__ gtb,
    const int* __restrict__ gtl, float* __restrict__ probs_sum,
    double* __restrict__ accs)
{
  __shared__ float s_gx[GG], s_gy[GG], s_ming[GG];
  __shared__ float s_ogx[GG], s_ogy[GG];
  __shared__ unsigned s_spec[GG], s_ospec[GG];
  __shared__ int s_ord[GG], s_qs[GG];
  __shared__ double s_rd[8];

  const int bid  = blockIdx.x;
  const int tid  = threadIdx.x;
  const int lane = tid & 63;
  const int wv   = tid >> 6;
  const float FINF = __builtin_inff();

  if (bid < GBLK) {
    // ================= greedy assignment, one batch per block =============
    // All 4 waves run the serial chain redundantly (identical deterministic
    // results); no cross-wave traffic inside the 100-iteration loop.
    const int b = bid;
    // lane-contiguous query chunks: lanes 0-3 own 15 q's, lanes 4-63 own 14.
    // lane order == q order, so lowest-lane tie-break == lowest-q tie-break.
    const int cnt    = lane < 4 ? 15 : 14;
    const int qstart = lane < 4 ? lane * 15 : 60 + (lane - 4) * 14;
    float qx[15], qy[15];   // invalid slots carry +inf -> dist=+inf, never win
    #pragma unroll
    for (int k = 0; k < 15; ++k) {
      int q = qstart + ((k < cnt) ? k : 0);
      float2 c2 = ((const float2*)qcen)[(size_t)b * QQ + q];
      qx[k] = (k < cnt) ? c2.x : FINF;
      qy[k] = (k < cnt) ? c2.y : 0.f;
    }
    if (tid < GG) {
      s_gx[tid] = gtb[((size_t)b * GG + tid) * 5 + 0];
      s_gy[tid] = gtb[((size_t)b * GG + tid) * 5 + 1];
    }
    __syncthreads();

    // setup: per GT, GLOBAL packed argmin (min key for argsort + speculative
    // winner (wl,wk) for the chain). packed = (d_bits & ~15) | k; uint order
    // == float order (d >= 0); lowest lane (ballot+ffs) == lowest q.
    for (int g = wv * 25; g < (wv + 1) * 25; ++g) {
      float bx = s_gx[g], by = s_gy[g];
      unsigned p[16];
      p[15] = 0xFFFFFFFFu;
      #pragma unroll
      for (int k = 0; k < 15; ++k) {
        float dx = bx - qx[k], dy = by - qy[k];
        float dd = fmaf(dy, dy, dx * dx);
        p[k] = (__float_as_uint(dd) & 0xFFFFFFF0u) | (unsigned)k;
      }
      #pragma unroll
      for (int s = 8; s >= 1; s >>= 1)
        #pragma unroll
        for (int k = 0; k < 8; ++k)
          if (k < s) p[k] = p[k] < p[k + s] ? p[k] : p[k + s];
      unsigned wm = dpp_umin64(p[0]);
      wm = (unsigned)__builtin_amdgcn_readlane((int)wm, 63);
      unsigned long long ball = __ballot(p[0] == wm);
      int wl = __ffsll((long long)ball) - 1;
      if (lane == 0) {
        s_ming[g] = __uint_as_float(wm & 0xFFFFFFF0u);  // truncated min dist
        s_spec[g] = (unsigned)((wl << 4) | (int)(wm & 15u));
      }
    }
    __syncthreads();

    // stable argsort rank (value, index)
    if (tid < GG) {
      float m = s_ming[tid];
      int r = 0;
      for (int j = 0; j < GG; ++j) {
        float mj = s_ming[j];
        r += (mj < m) || (mj == m && j < tid);
      }
      s_ord[r] = tid;
    }
    __syncthreads();
    // ordered coords + ordered speculative winners
    if (tid < GG) {
      int g = s_ord[tid];
      s_ogx[tid]   = s_gx[g];
      s_ogy[tid]   = s_gy[g];
      s_ospec[tid] = s_spec[g];
    }
    __syncthreads();

    // specs into 2 VGPRs (lane l holds spec[l] and spec[64+l]); chain reads
    // them via uniform readlane -> zero LDS on the fast path.
    unsigned sv0 = s_ospec[lane];
    unsigned sv1 = s_ospec[(64 + lane) < GG ? (64 + lane) : (GG - 1)];

    // greedy chain. Fast path: global winner unused -> take it (~15 inst).
    // Fallback (collision): full used-masked packed argmin (R11 path).
    unsigned used = 0;
    for (int i = 0; i < GG; ++i) {
      unsigned spec = (unsigned)__builtin_amdgcn_readlane(
          (int)(i < 64 ? sv0 : sv1), i & 63);
      int wl = (int)(spec >> 4);
      int wk = (int)(spec & 15u);
      unsigned uwl = (unsigned)__builtin_amdgcn_readlane((int)used, wl);
      if ((uwl >> wk) & 1u) {   // wave-uniform branch: collision -> recompute
        float bx = s_ogx[i], by = s_ogy[i];
        unsigned p[16];
        p[15] = 0xFFFFFFFFu;
        #pragma unroll
        for (int k = 0; k < 15; ++k) {
          float dx = bx - qx[k], dy = by - qy[k];
          float dd = fmaf(dy, dy, dx * dx);
          unsigned pk = (__float_as_uint(dd) & 0xFFFFFFF0u) | (unsigned)k;
          p[k] = ((used >> k) & 1u) ? 0xFFFFFFFFu : pk;
        }
        #pragma unroll
        for (int s = 8; s >= 1; s >>= 1)
          #pragma unroll
          for (int k = 0; k < 8; ++k)
            if (k < s) p[k] = p[k] < p[k + s] ? p[k] : p[k + s];
        unsigned wm = dpp_umin64(p[0]);
        wm = (unsigned)__builtin_amdgcn_readlane((int)wm, 63);
        unsigned long long ball = __ballot(p[0] == wm);
        wl = __ffsll((long long)ball) - 1;
        wk = (int)(wm & 15u);
      }
      int qwin = (wl < 4 ? wl * 15 : 60 + (wl - 4) * 14) + wk;
      if (lane == wl) used |= (1u << wk);
      if (tid == 0) s_qs[i] = qwin;
    }
    __syncthreads();

    // corrections: focal t=0 -> t=1 patch + smooth-L1 box loss on positives
    double dcls = 0.0, dbox = 0.0;
    if (tid < GG) {
      int g   = s_ord[tid];
      int q   = s_qs[tid];
      int lab = gtl[b * GG + g];
      float x = logits[((size_t)b * QQ + q) * CC + lab];
      float p, sp; sig_sp(x, p, sp);
      float omp = 1.f - p;
      dcls = (double)(0.25f * omp * omp * (sp - x)) -
             (double)(0.75f * p * p * sp);
      float bs = 0.f;
      #pragma unroll
      for (int j = 0; j < 5; ++j) {
        float diff = boxes[((size_t)b * QQ + q) * 5 + j] -
                     gtb[((size_t)b * GG + g) * 5 + j];
        float ad = fabsf(diff);
        bs += (ad < 1.f) ? 0.5f * diff * diff : ad - 0.5f;
      }
      dbox = (double)bs;
    }
    #pragma unroll
    for (int off = 32; off; off >>= 1) {
      dcls += __shfl_xor(dcls, off, 64);
      dbox += __shfl_xor(dbox, off, 64);
    }
    if (lane == 0) { s_rd[wv] = dcls; s_rd[4 + wv] = dbox; }
    __syncthreads();
    if (tid == 0) {
      atomicAdd(&accs[0], s_rd[0] + s_rd[1] + s_rd[2] + s_rd[3]);
      atomicAdd(&accs[1], s_rd[4] + s_rd[5] + s_rd[6] + s_rd[7]);
    }
  } else {
    // ================= streaming: focal base + sigmoid row-sums ===========
    int sid = bid - GBLK;
    int ct = sid % CT;
    int b  = (sid / CT) % BB;
    int qk = sid / (CT * BB);
    int c  = ct * 256 + tid;
    float s_sig = 0.f, s_foc = 0.f;
    if (c < CC) {
      const float* base = logits + ((size_t)b * QQ + (size_t)qk * QPC) * CC + c;
      // group-of-5 unroll: 5 independent loads in flight per group (MLP)
      for (int i0 = 0; i0 < QPC; i0 += 5) {
        float xs[5];
        #pragma unroll
        for (int u = 0; u < 5; ++u) xs[u] = base[(size_t)(i0 + u) * CC];
        #pragma unroll
        for (int u = 0; u < 5; ++u) {
          float p, sp; sig_sp(xs[u], p, sp);
          s_sig += p;
          s_foc += 0.75f * p * p * sp;   // t=0 focal term
        }
      }
      atomicAdd(&probs_sum[b * CC + c], s_sig);
    }
    double v = (double)s_foc;
    #pragma unroll
    for (int off = 32; off; off >>= 1) v += __shfl_xor(v, off, 64);
    if (lane == 0) s_rd[wv] = v;
    __syncthreads();
    if (tid == 0) atomicAdd(&accs[0], s_rd[0] + s_rd[1] + s_rd[2] + s_rd[3]);
  }
}

// hier: per row c of R: part_c = x_c * (x_c * rowsum_c - dot(R_c, x)) summed
// over 16 batches; R read exactly once.
__global__ __launch_bounds__(256) void hier_kernel(
    const float* __restrict__ Rm, const float* __restrict__ probs_sum,
    double* __restrict__ accs)
{
  __shared__ float s_x[BB * CC];   // 77 KB
  __shared__ double s_rd[4];
  const int tid = threadIdx.x, lane = tid & 63, wv = tid >> 6;
  const float inv_q = 1.f / (float)QQ;
  constexpr int N4 = BB * CC / 4;  // 19248/4, exact
  const float4* src4 = (const float4*)probs_sum;
  for (int i = tid; i < N4; i += 256) {
    float4 v = src4[i];
    s_x[i * 4 + 0] = v.x * inv_q;
    s_x[i * 4 + 1] = v.y * inv_q;
    s_x[i * 4 + 2] = v.z * inv_q;
    s_x[i * 4 + 3] = v.w * inv_q;
  }
  __syncthreads();

  int c = blockIdx.x * 4 + wv;
  double part = 0.0;
  if (c < CC) {
    const float* row = Rm + (size_t)c * CC;
    float rs = 0.f, dot[BB];
    #pragma unroll
    for (int bb = 0; bb < BB; ++bb) dot[bb] = 0.f;
    for (int d = lane; d < CC; d += 64) {
      float r = row[d];
      rs += r;
      #pragma unroll
      for (int bb = 0; bb < BB; ++bb) dot[bb] = fmaf(r, s_x[bb * CC + d], dot[bb]);
    }
    #pragma unroll
    for (int off = 32; off; off >>= 1) {
      rs += __shfl_xor(rs, off, 64);
      #pragma unroll
      for (int bb = 0; bb < BB; ++bb) dot[bb] += __shfl_xor(dot[bb], off, 64);
    }
    if (lane == 0) {
      #pragma unroll
      for (int bb = 0; bb < BB; ++bb) {
        float xc = s_x[bb * CC + c];
        part += (double)xc * ((double)xc * (double)rs - (double)dot[bb]);
      }
    }
  }
  if (lane == 0) s_rd[wv] = part;
  __syncthreads();
  if (tid == 0) atomicAdd(&accs[2], s_rd[0] + s_rd[1] + s_rd[2] + s_rd[3]);
}

__global__ void finalize_kernel(const double* __restrict__ accs,
                                float* __restrict__ out)
{
  if (threadIdx.x == 0 && blockIdx.x == 0) {
    double cls  = accs[0] / (double)((size_t)BB * QQ * CC);
    double box  = accs[1] / 8000.0;   // sum(m)*5 = 16*100*5, all GTs assigned
    double hier = accs[2] / (double)BB;
    double total = 1.0 * cls + 5.0 * box + 0.1 * hier;
    out[0] = (float)total;
    out[1] = (float)cls;
    out[2] = (float)box;
    out[3] = (float)hier;
  }
}

extern "C" void kernel_launch(void* const* d_in, const int* in_sizes, int n_in,
                              void* d_out, int out_size, void* d_ws, size_t ws_size,
                              hipStream_t stream) {
  const float* logits = (const float*)d_in[0];
  const float* boxes  = (const float*)d_in[1];
  const float* qcen   = (const float*)d_in[2];
  const float* gtb    = (const float*)d_in[3];
  const int*   gtl    = (const int*)d_in[4];
  const float* relm   = (const float*)d_in[5];

  float*  probs_sum = (float*)d_ws;                   // 16*1203 floats
  double* accs      = (double*)((char*)d_ws + 80000); // 8B aligned

  hipMemsetAsync(d_ws, 0, 80000 + 4 * sizeof(double), stream);

  fused_main<<<GBLK + ABLK, 256, 0, stream>>>(logits, boxes, qcen, gtb, gtl,
                                              probs_sum, accs);
  hier_kernel<<<(CC + 3) / 4, 256, 0, stream>>>(relm, probs_sum, accs);
  finalize_kernel<<<1, 64, 0, stream>>>(accs, (float*)d_out);
}